// Round 1
// 2842.296 us; speedup vs baseline: 1.7499x; 1.7499x over previous
//
#include <hip/hip_runtime.h>
#include <hip/hip_cooperative_groups.h>
#include <math.h>

#define BB 16
#define CC 192
#define NF 192
#define HH 128
#define WW 128
#define G4 768
#define KTOT 768
#define LDA 776                 // A LDS row stride in shorts (768 + 8 pad)
#define NJB 12                  // j-blocks (NF/16)
#define GRIDSZ (NJB * BB)       // 192 blocks
#define SMEM_BYTES ((64 * LDA + 128 * 24) * 2)

typedef __bf16 bf16x8 __attribute__((ext_vector_type(8)));
typedef float  f32x4  __attribute__((ext_vector_type(4)));

// Per-batch barrier state: one slot per batch, 256B apart to avoid line sharing.
// Monotonic phase (flag = last completed step+1) avoids sense-reversal races.
// Zeroed each launch by prep_weights (graph-replay safe).
__device__ unsigned g_bar_cnt[BB * 64];
__device__ unsigned g_bar_flag[BB * 64];

__device__ __forceinline__ float hsig(float v) {
    float y = fmaf(0.2f, v, 0.5f);
    return fminf(fmaxf(y, 0.f), 1.f);
}

__device__ __forceinline__ unsigned short f2bf(float f) {
    unsigned int u = __float_as_uint(f);
    u += 0x7fffu + ((u >> 16) & 1u);   // RNE
    return (unsigned short)(u >> 16);
}

// Wc[row=g*NF+j][k]: k<192 masked input weights; k=192+d*192+c = U tap d.
__global__ void prep_weights(const float* __restrict__ Wf,
                             const float* __restrict__ Uf,
                             unsigned short* __restrict__ Wc) {
    int idx = blockIdx.x * blockDim.x + threadIdx.x;
    if (idx < BB) {                      // reset per-batch barriers each launch
        g_bar_cnt[idx * 64]  = 0u;
        g_bar_flag[idx * 64] = 0u;
    }
    if (idx >= G4 * KTOT) return;
    int row = idx / KTOT;
    int k   = idx - row * KTOT;
    float v;
    if (k < CC) {
        int lim = row < 64 ? 64 : (row < 128 ? 128 : 192);
        v = (k < lim) ? Wf[row * CC + k] : 0.f;
    } else {
        int kp = k - CC;
        int d  = kp / CC;
        int c  = kp - d * CC;
        v = Uf[((size_t)row * CC + c) * 3 + d];
    }
    Wc[idx] = f2bf(v);
}

// x-part of Bsrc: Bsrc[t][b][w][c] = bf16(x[b][c][t][w]), c in [0,192).
__global__ void prep_bx(const float* __restrict__ x, unsigned short* __restrict__ Bsrc) {
    int idx = blockIdx.x * blockDim.x + threadIdx.x;   // over 128*16*128
    if (idx >= HH * BB * WW) return;
    int w = idx & (WW - 1);
    int r = idx >> 7;
    int b = r & (BB - 1);
    int t = r >> 4;
    const float* xp = x + ((size_t)b * CC * HH + t) * WW + w;
    unsigned short* dp = Bsrc + (size_t)idx * KTOT;
#pragma unroll
    for (int cc = 0; cc < CC / 8; ++cc) {
        unsigned short v[8];
#pragma unroll
        for (int i = 0; i < 8; ++i)
            v[i] = f2bf(xp[(size_t)(cc * 8 + i) * (HH * WW)]);
        *(uint4*)(dp + cc * 8) = *(uint4*)v;
    }
}

// Zero the never-written halo slots for all t: [t][b][0][192..384) and [t][b][127][576..768).
__global__ void prep_bh_oob(unsigned short* __restrict__ Bsrc) {
    int idx = blockIdx.x * blockDim.x + threadIdx.x;   // 128*16*384
    if (idx >= HH * BB * 384) return;
    int u = idx % 384;
    int r = idx / 384;
    int b = r & (BB - 1);
    int t = r >> 4;
    size_t base = ((size_t)(t * BB + b) * WW) * KTOT;
    size_t off = (u < 192) ? (size_t)0 * KTOT + 192 + u
                           : (size_t)127 * KTOT + 384 + u;   // 576 + (u-192)
    Bsrc[base + off] = 0;
}

// t=0 h-part from init_h: Bsrc[0][b][w][192+d*192+c] = init_h[c][w+d-1] (0 if OOB).
__global__ void prep_bh0(const float* __restrict__ init_h, unsigned short* __restrict__ Bsrc) {
    int idx = blockIdx.x * blockDim.x + threadIdx.x;   // 16*128*576
    if (idx >= BB * WW * 576) return;
    int kp = idx % 576;
    int r  = idx / 576;
    int w  = r & (WW - 1);
    int b  = r >> 7;
    int d  = kp / CC;
    int c  = kp - d * CC;
    int wt = w + d - 1;
    float v = (wt >= 0 && wt < WW) ? init_h[c * WW + wt] : 0.f;
    Bsrc[((size_t)b * WW + w) * KTOT + CC + kp] = f2bf(v);
}

// Persistent LSTM: all 128 steps. 192 blocks x 256 threads.
// Block = (j-tile of 16, batch b); M=64 rows (4 gates x 16 j), N=128 (all w).
// Sync: per-batch 12-block barrier (batches are independent — grid.sync was
// 16x over-synchronized lock-step and dominated the step time).
__global__ __launch_bounds__(256, 1) void lstm_persist(
    const unsigned short* __restrict__ Wc,
    unsigned short* __restrict__ Bsrc,
    const float* __restrict__ bias,
    const float* __restrict__ init_c,
    float* __restrict__ out)
{
    extern __shared__ unsigned short smem[];
    unsigned short (*Alds)[LDA] = (unsigned short(*)[LDA])smem;
    unsigned short (*hT)[24]    = (unsigned short(*)[24])(smem + 64 * LDA);

    const int tid  = threadIdx.x;
    const int wave = tid >> 6;
    const int lane = tid & 63;
    const int m    = lane & 15;
    const int q    = lane >> 4;
    const int jb   = blockIdx.x % NJB;
    const int b    = blockIdx.x / NJB;
    const int j0   = jb * 16;

    // ---- load A once: row r -> Wc row (r>>4)*NF + j0 + (r&15) ----
    for (int u = tid; u < 64 * 96; u += 256) {
        int r  = u / 96;
        int ko = (u - r * 96) * 8;
        int grow = (r >> 4) * NF + j0 + (r & 15);
        *(uint4*)&Alds[r][ko] = *(const uint4*)(Wc + (size_t)grow * KTOT + ko);
    }
    // ---- bias & c-state in registers ----
    float breg[4][4];
#pragma unroll
    for (int g = 0; g < 4; ++g)
#pragma unroll
        for (int r = 0; r < 4; ++r)
            breg[g][r] = bias[g * NF + j0 + q * 4 + r];
    float creg[2][4];
#pragma unroll
    for (int n = 0; n < 2; ++n)
#pragma unroll
        for (int r = 0; r < 4; ++r)
            creg[n][r] = init_c[(j0 + q * 4 + r) * WW + wave * 32 + n * 16 + m];
    __syncthreads();

    for (int t = 0; t < HH; ++t) {
        f32x4 acc[4][2];
#pragma unroll
        for (int g = 0; g < 4; ++g)
#pragma unroll
            for (int n = 0; n < 2; ++n)
                acc[g][n] = (f32x4){breg[g][0], breg[g][1], breg[g][2], breg[g][3]};

        const unsigned short* Bb  = Bsrc + ((size_t)(t * BB + b) * WW) * KTOT;
        const unsigned short* Bn0 = Bb + (size_t)(wave * 32 + m) * KTOT;
        const unsigned short* Bn1 = Bn0 + (size_t)16 * KTOT;

#pragma unroll 8
        for (int kc = 0; kc < KTOT / 32; ++kc) {
            const int k = kc * 32 + q * 8;
            bf16x8 b0 = *(const bf16x8*)(Bn0 + k);
            bf16x8 b1 = *(const bf16x8*)(Bn1 + k);
            bf16x8 a0 = *(const bf16x8*)&Alds[ 0 + m][k];
            bf16x8 a1 = *(const bf16x8*)&Alds[16 + m][k];
            bf16x8 a2 = *(const bf16x8*)&Alds[32 + m][k];
            bf16x8 a3 = *(const bf16x8*)&Alds[48 + m][k];
            acc[0][0] = __builtin_amdgcn_mfma_f32_16x16x32_bf16(a0, b0, acc[0][0], 0, 0, 0);
            acc[0][1] = __builtin_amdgcn_mfma_f32_16x16x32_bf16(a0, b1, acc[0][1], 0, 0, 0);
            acc[1][0] = __builtin_amdgcn_mfma_f32_16x16x32_bf16(a1, b0, acc[1][0], 0, 0, 0);
            acc[1][1] = __builtin_amdgcn_mfma_f32_16x16x32_bf16(a1, b1, acc[1][1], 0, 0, 0);
            acc[2][0] = __builtin_amdgcn_mfma_f32_16x16x32_bf16(a2, b0, acc[2][0], 0, 0, 0);
            acc[2][1] = __builtin_amdgcn_mfma_f32_16x16x32_bf16(a2, b1, acc[2][1], 0, 0, 0);
            acc[3][0] = __builtin_amdgcn_mfma_f32_16x16x32_bf16(a3, b0, acc[3][0], 0, 0, 0);
            acc[3][1] = __builtin_amdgcn_mfma_f32_16x16x32_bf16(a3, b1, acc[3][1], 0, 0, 0);
        }

        // ---- epilogue: gates + c/h update, h -> LDS transpose ----
#pragma unroll
        for (int n = 0; n < 2; ++n) {
            const int w = wave * 32 + n * 16 + m;
#pragma unroll
            for (int r = 0; r < 4; ++r) {
                const int j = j0 + q * 4 + r;
                float og = hsig(acc[0][n][r]);
                float fg = hsig(acc[1][n][r]);
                float ig = hsig(acc[2][n][r]);
                float gg = tanhf(acc[3][n][r]);
                float cn = fmaf(fg, creg[n][r], ig * gg);
                creg[n][r] = cn;
                float hn = og * tanhf(cn);
                out[(((size_t)b * NF + j) * HH + t) * WW + w] = hn;
                hT[w][q * 4 + r] = f2bf(hn);
            }
        }
        __syncthreads();

        // ---- scatter h into next step's B source, then per-batch barrier ----
        if (t < HH - 1) {
            unsigned short* Bn = Bsrc + ((size_t)((t + 1) * BB + b) * WW) * KTOT;
            for (int u = tid; u < 384; u += 256) {
                int d  = u >> 7;
                int w2 = u & 127;
                int w  = w2 + d - 1;
                if (w >= 0 && w < WW) {
                    uint4 lo = *(uint4*)&hT[w][0];
                    uint4 hi = *(uint4*)&hT[w][8];
                    unsigned short* dst = Bn + (size_t)w2 * KTOT + CC + d * CC + j0;
                    *(uint4*)dst       = lo;
                    *(uint4*)(dst + 8) = hi;
                }
            }
            // __syncthreads drains each wave's stores to L2 (vmcnt(0) before
            // s_barrier); thread 0's ACQ_REL agent-scope RMW then flushes L2
            // to the coherence point (cross-XCD visibility of the h-exchange).
            __syncthreads();
            if (tid == 0) {
                unsigned* cnt  = &g_bar_cnt[b * 64];
                unsigned* flag = &g_bar_flag[b * 64];
                const unsigned phase = (unsigned)(t + 1);
                unsigned arrived = __hip_atomic_fetch_add(
                    cnt, 1u, __ATOMIC_ACQ_REL, __HIP_MEMORY_SCOPE_AGENT) + 1u;
                if (arrived == NJB) {
                    __hip_atomic_store(cnt, 0u, __ATOMIC_RELAXED,
                                       __HIP_MEMORY_SCOPE_AGENT);
                    __hip_atomic_store(flag, phase, __ATOMIC_RELEASE,
                                       __HIP_MEMORY_SCOPE_AGENT);
                } else {
                    // relaxed agent polls read the coherence point directly;
                    // one acquire fence on exit invalidates L1/L2 once.
                    while (__hip_atomic_load(flag, __ATOMIC_RELAXED,
                                             __HIP_MEMORY_SCOPE_AGENT) < phase)
                        __builtin_amdgcn_s_sleep(2);
                    __builtin_amdgcn_fence(__ATOMIC_ACQUIRE, "agent");
                }
            }
            __syncthreads();
        }
    }
}

extern "C" void kernel_launch(void* const* d_in, const int* in_sizes, int n_in,
                              void* d_out, int out_size, void* d_ws, size_t ws_size,
                              hipStream_t stream) {
    const float* x      = (const float*)d_in[0];
    const float* W_iof  = (const float*)d_in[1];
    const float* U_iof  = (const float*)d_in[2];
    const float* b_iof  = (const float*)d_in[3];
    const float* init_h = (const float*)d_in[4];
    const float* init_c = (const float*)d_in[5];
    float* out = (float*)d_out;

    unsigned short* Wc   = (unsigned short*)d_ws;                       // 768*768 bf16
    unsigned short* Bsrc = Wc + (size_t)G4 * KTOT;                      // 128*16*128*768 bf16

    prep_weights<<<(G4 * KTOT + 255) / 256, 256, 0, stream>>>(W_iof, U_iof, Wc);
    prep_bx<<<(HH * BB * WW + 255) / 256, 256, 0, stream>>>(x, Bsrc);
    prep_bh_oob<<<(HH * BB * 384 + 255) / 256, 256, 0, stream>>>(Bsrc);
    prep_bh0<<<(BB * WW * 576 + 255) / 256, 256, 0, stream>>>(init_h, Bsrc);

    const unsigned short* Wcp = Wc;
    unsigned short* Bsp = Bsrc;
    const float* bp = b_iof;
    const float* icp = init_c;
    float* op = out;
    void* args[] = {&Wcp, &Bsp, &bp, &icp, &op};
    // Cooperative launch kept only for the co-residency guarantee (spin-safety
    // of the per-batch barriers); no cg::grid sync is used.
    hipLaunchCooperativeKernel((const void*)lstm_persist, dim3(GRIDSZ), dim3(256),
                               args, SMEM_BYTES, stream);
}

// Round 2
// 2491.291 us; speedup vs baseline: 1.9964x; 1.1409x over previous
//
#include <hip/hip_runtime.h>
#include <math.h>

#define BB 16
#define CC 192
#define NF 192
#define HH 128
#define WW 128
#define G4 768
#define KTOT 768
#define LDA 776                 // A LDS row stride in shorts (768 + 8 pad)
#define NJB 12                  // j-blocks (NF/16)
#define GRIDSZ (NJB * BB)       // 192 blocks
#define SMEM_BYTES ((64 * LDA + 128 * 24) * 2)

typedef __bf16 bf16x8 __attribute__((ext_vector_type(8)));
typedef float  f32x4  __attribute__((ext_vector_type(4)));

// Per-batch MONOTONIC arrival counter (12 arrivals per step, never reset
// mid-kernel; max 12*127 = 1524). Relaxed agent atomics only — no wbl2/inv.
// Slots 256B apart to avoid line sharing. Zeroed each launch by prep_weights.
__device__ unsigned g_cnt[BB * 64];

__device__ __forceinline__ float hsig(float v) {
    float y = fmaf(0.2f, v, 0.5f);
    return fminf(fmaxf(y, 0.f), 1.f);
}

__device__ __forceinline__ unsigned short f2bf(float f) {
    unsigned int u = __float_as_uint(f);
    u += 0x7fffu + ((u >> 16) & 1u);   // RNE
    return (unsigned short)(u >> 16);
}

// Wc[row=g*NF+j][k]: k<192 masked input weights; k=192+d*192+c = U tap d.
__global__ void prep_weights(const float* __restrict__ Wf,
                             const float* __restrict__ Uf,
                             unsigned short* __restrict__ Wc) {
    int idx = blockIdx.x * blockDim.x + threadIdx.x;
    if (idx < BB)                        // reset per-batch counters each launch
        g_cnt[idx * 64] = 0u;
    if (idx >= G4 * KTOT) return;
    int row = idx / KTOT;
    int k   = idx - row * KTOT;
    float v;
    if (k < CC) {
        int lim = row < 64 ? 64 : (row < 128 ? 128 : 192);
        v = (k < lim) ? Wf[row * CC + k] : 0.f;
    } else {
        int kp = k - CC;
        int d  = kp / CC;
        int c  = kp - d * CC;
        v = Uf[((size_t)row * CC + c) * 3 + d];
    }
    Wc[idx] = f2bf(v);
}

// x-part of Bsrc: Bsrc[t][b][w][c] = bf16(x[b][c][t][w]), c in [0,192).
__global__ void prep_bx(const float* __restrict__ x, unsigned short* __restrict__ Bsrc) {
    int idx = blockIdx.x * blockDim.x + threadIdx.x;   // over 128*16*128
    if (idx >= HH * BB * WW) return;
    int w = idx & (WW - 1);
    int r = idx >> 7;
    int b = r & (BB - 1);
    int t = r >> 4;
    const float* xp = x + ((size_t)b * CC * HH + t) * WW + w;
    unsigned short* dp = Bsrc + (size_t)idx * KTOT;
#pragma unroll
    for (int cc = 0; cc < CC / 8; ++cc) {
        unsigned short v[8];
#pragma unroll
        for (int i = 0; i < 8; ++i)
            v[i] = f2bf(xp[(size_t)(cc * 8 + i) * (HH * WW)]);
        *(uint4*)(dp + cc * 8) = *(uint4*)v;
    }
}

// Zero the never-written halo slots for all t: [t][b][0][192..384) and [t][b][127][576..768).
// NOTE: these 64B lines are disjoint from the step-written h lines (boundaries
// at byte 768 / 1152 are line-aligned), so cached reads of them are always safe.
__global__ void prep_bh_oob(unsigned short* __restrict__ Bsrc) {
    int idx = blockIdx.x * blockDim.x + threadIdx.x;   // 128*16*384
    if (idx >= HH * BB * 384) return;
    int u = idx % 384;
    int r = idx / 384;
    int b = r & (BB - 1);
    int t = r >> 4;
    size_t base = ((size_t)(t * BB + b) * WW) * KTOT;
    size_t off = (u < 192) ? (size_t)0 * KTOT + 192 + u
                           : (size_t)127 * KTOT + 384 + u;   // 576 + (u-192)
    Bsrc[base + off] = 0;
}

// t=0 h-part from init_h: Bsrc[0][b][w][192+d*192+c] = init_h[c][w+d-1] (0 if OOB).
__global__ void prep_bh0(const float* __restrict__ init_h, unsigned short* __restrict__ Bsrc) {
    int idx = blockIdx.x * blockDim.x + threadIdx.x;   // 16*128*576
    if (idx >= BB * WW * 576) return;
    int kp = idx % 576;
    int r  = idx / 576;
    int w  = r & (WW - 1);
    int b  = r >> 7;
    int d  = kp / CC;
    int c  = kp - d * CC;
    int wt = w + d - 1;
    float v = (wt >= 0 && wt < WW) ? init_h[c * WW + wt] : 0.f;
    Bsrc[((size_t)b * WW + w) * KTOT + CC + kp] = f2bf(v);
}

// Persistent LSTM: all 128 steps. 192 blocks x 256 threads.
// Block = (j-tile of 16, batch b); M=64 rows (4 gates x 16 j), N=128 (all w).
// Sync design (fence-free):
//  - h-scatter = relaxed agent atomic 8B stores (sc0 sc1, write-through to LLC,
//    no dirty L2) -> __syncthreads' vmcnt(0) drains them to the coherence point.
//  - arrive = relaxed agent fetch_add on a monotonic per-batch counter.
//  - wait   = relaxed agent polls (cnt >= 12*t); NO acquire fence / L2 inv:
//    every h line of slice t+1 is written once (L2-bypassing) and first read
//    after the barrier, so no cache can hold a stale copy. Launch-time
//    system-acquire invalidate handles cross-replay staleness.
//  - x-part GEMM (k<192, prep data only) runs BEFORE the wait to overlap
//    the straggler window.
__global__ __launch_bounds__(256, 1) void lstm_persist(
    const unsigned short* __restrict__ Wc,
    unsigned short* __restrict__ Bsrc,
    const float* __restrict__ bias,
    const float* __restrict__ init_c,
    float* __restrict__ out)
{
    extern __shared__ unsigned short smem[];
    unsigned short (*Alds)[LDA] = (unsigned short(*)[LDA])smem;
    unsigned short (*hT)[24]    = (unsigned short(*)[24])(smem + 64 * LDA);

    const int tid  = threadIdx.x;
    const int wave = tid >> 6;
    const int lane = tid & 63;
    const int m    = lane & 15;
    const int q    = lane >> 4;
    const int jb   = blockIdx.x % NJB;
    const int b    = blockIdx.x / NJB;
    const int j0   = jb * 16;
    unsigned* const cntp = &g_cnt[b * 64];

    // ---- load A once: row r -> Wc row (r>>4)*NF + j0 + (r&15) ----
    for (int u = tid; u < 64 * 96; u += 256) {
        int r  = u / 96;
        int ko = (u - r * 96) * 8;
        int grow = (r >> 4) * NF + j0 + (r & 15);
        *(uint4*)&Alds[r][ko] = *(const uint4*)(Wc + (size_t)grow * KTOT + ko);
    }
    // ---- bias & c-state in registers ----
    float breg[4][4];
#pragma unroll
    for (int g = 0; g < 4; ++g)
#pragma unroll
        for (int r = 0; r < 4; ++r)
            breg[g][r] = bias[g * NF + j0 + q * 4 + r];
    float creg[2][4];
#pragma unroll
    for (int n = 0; n < 2; ++n)
#pragma unroll
        for (int r = 0; r < 4; ++r)
            creg[n][r] = init_c[(j0 + q * 4 + r) * WW + wave * 32 + n * 16 + m];
    __syncthreads();

    for (int t = 0; t < HH; ++t) {
        f32x4 acc[4][2];
#pragma unroll
        for (int g = 0; g < 4; ++g)
#pragma unroll
            for (int n = 0; n < 2; ++n)
                acc[g][n] = (f32x4){breg[g][0], breg[g][1], breg[g][2], breg[g][3]};

        const unsigned short* Bb  = Bsrc + ((size_t)(t * BB + b) * WW) * KTOT;
        const unsigned short* Bn0 = Bb + (size_t)(wave * 32 + m) * KTOT;
        const unsigned short* Bn1 = Bn0 + (size_t)16 * KTOT;

        // ---- x-part GEMM (k < 192): no dependency on the h-exchange ----
#pragma unroll 6
        for (int kc = 0; kc < 6; ++kc) {
            const int k = kc * 32 + q * 8;
            bf16x8 b0 = *(const bf16x8*)(Bn0 + k);
            bf16x8 b1 = *(const bf16x8*)(Bn1 + k);
            bf16x8 a0 = *(const bf16x8*)&Alds[ 0 + m][k];
            bf16x8 a1 = *(const bf16x8*)&Alds[16 + m][k];
            bf16x8 a2 = *(const bf16x8*)&Alds[32 + m][k];
            bf16x8 a3 = *(const bf16x8*)&Alds[48 + m][k];
            acc[0][0] = __builtin_amdgcn_mfma_f32_16x16x32_bf16(a0, b0, acc[0][0], 0, 0, 0);
            acc[0][1] = __builtin_amdgcn_mfma_f32_16x16x32_bf16(a0, b1, acc[0][1], 0, 0, 0);
            acc[1][0] = __builtin_amdgcn_mfma_f32_16x16x32_bf16(a1, b0, acc[1][0], 0, 0, 0);
            acc[1][1] = __builtin_amdgcn_mfma_f32_16x16x32_bf16(a1, b1, acc[1][1], 0, 0, 0);
            acc[2][0] = __builtin_amdgcn_mfma_f32_16x16x32_bf16(a2, b0, acc[2][0], 0, 0, 0);
            acc[2][1] = __builtin_amdgcn_mfma_f32_16x16x32_bf16(a2, b1, acc[2][1], 0, 0, 0);
            acc[3][0] = __builtin_amdgcn_mfma_f32_16x16x32_bf16(a3, b0, acc[3][0], 0, 0, 0);
            acc[3][1] = __builtin_amdgcn_mfma_f32_16x16x32_bf16(a3, b1, acc[3][1], 0, 0, 0);
        }

        // ---- wait for all 12 j-blocks' h-scatter of this step ----
        if (t > 0) {
            const unsigned need = (unsigned)(NJB * t);
            while (__hip_atomic_load(cntp, __ATOMIC_RELAXED,
                                     __HIP_MEMORY_SCOPE_AGENT) < need)
                __builtin_amdgcn_s_sleep(1);
            // compiler-only ordering: keep h loads below the spin (no L2 inv).
            __builtin_amdgcn_fence(__ATOMIC_ACQUIRE, "workgroup");
        }

        // ---- h-part GEMM (k >= 192) ----
#pragma unroll 6
        for (int kc = 6; kc < KTOT / 32; ++kc) {
            const int k = kc * 32 + q * 8;
            bf16x8 b0 = *(const bf16x8*)(Bn0 + k);
            bf16x8 b1 = *(const bf16x8*)(Bn1 + k);
            bf16x8 a0 = *(const bf16x8*)&Alds[ 0 + m][k];
            bf16x8 a1 = *(const bf16x8*)&Alds[16 + m][k];
            bf16x8 a2 = *(const bf16x8*)&Alds[32 + m][k];
            bf16x8 a3 = *(const bf16x8*)&Alds[48 + m][k];
            acc[0][0] = __builtin_amdgcn_mfma_f32_16x16x32_bf16(a0, b0, acc[0][0], 0, 0, 0);
            acc[0][1] = __builtin_amdgcn_mfma_f32_16x16x32_bf16(a0, b1, acc[0][1], 0, 0, 0);
            acc[1][0] = __builtin_amdgcn_mfma_f32_16x16x32_bf16(a1, b0, acc[1][0], 0, 0, 0);
            acc[1][1] = __builtin_amdgcn_mfma_f32_16x16x32_bf16(a1, b1, acc[1][1], 0, 0, 0);
            acc[2][0] = __builtin_amdgcn_mfma_f32_16x16x32_bf16(a2, b0, acc[2][0], 0, 0, 0);
            acc[2][1] = __builtin_amdgcn_mfma_f32_16x16x32_bf16(a2, b1, acc[2][1], 0, 0, 0);
            acc[3][0] = __builtin_amdgcn_mfma_f32_16x16x32_bf16(a3, b0, acc[3][0], 0, 0, 0);
            acc[3][1] = __builtin_amdgcn_mfma_f32_16x16x32_bf16(a3, b1, acc[3][1], 0, 0, 0);
        }

        // ---- epilogue: gates + c/h update, h -> LDS transpose ----
#pragma unroll
        for (int n = 0; n < 2; ++n) {
            const int w = wave * 32 + n * 16 + m;
#pragma unroll
            for (int r = 0; r < 4; ++r) {
                const int j = j0 + q * 4 + r;
                float og = hsig(acc[0][n][r]);
                float fg = hsig(acc[1][n][r]);
                float ig = hsig(acc[2][n][r]);
                float gg = tanhf(acc[3][n][r]);
                float cn = fmaf(fg, creg[n][r], ig * gg);
                creg[n][r] = cn;
                float hn = og * tanhf(cn);
                out[(((size_t)b * NF + j) * HH + t) * WW + w] = hn;
                hT[w][q * 4 + r] = f2bf(hn);
            }
        }
        __syncthreads();

        // ---- scatter h into next step's B source (L2-bypassing), arrive ----
        if (t < HH - 1) {
            unsigned short* Bn = Bsrc + ((size_t)((t + 1) * BB + b) * WW) * KTOT;
            for (int u = tid; u < 384; u += 256) {
                int d  = u >> 7;
                int w2 = u & 127;
                int w  = w2 + d - 1;
                if (w >= 0 && w < WW) {
                    const unsigned long long* s8 =
                        (const unsigned long long*)&hT[w][0];
                    unsigned long long* d8 = (unsigned long long*)
                        (Bn + (size_t)w2 * KTOT + CC + d * CC + j0);
#pragma unroll
                    for (int e = 0; e < 4; ++e)
                        __hip_atomic_store(d8 + e, s8[e], __ATOMIC_RELAXED,
                                           __HIP_MEMORY_SCOPE_AGENT);
                }
            }
            // vmcnt(0) inside __syncthreads drains the sc1 stores to the
            // coherence point for ALL waves before tid 0 publishes arrival.
            __syncthreads();
            if (tid == 0)
                __hip_atomic_fetch_add(cntp, 1u, __ATOMIC_RELAXED,
                                       __HIP_MEMORY_SCOPE_AGENT);
        }
    }
}

extern "C" void kernel_launch(void* const* d_in, const int* in_sizes, int n_in,
                              void* d_out, int out_size, void* d_ws, size_t ws_size,
                              hipStream_t stream) {
    const float* x      = (const float*)d_in[0];
    const float* W_iof  = (const float*)d_in[1];
    const float* U_iof  = (const float*)d_in[2];
    const float* b_iof  = (const float*)d_in[3];
    const float* init_h = (const float*)d_in[4];
    const float* init_c = (const float*)d_in[5];
    float* out = (float*)d_out;

    unsigned short* Wc   = (unsigned short*)d_ws;                       // 768*768 bf16
    unsigned short* Bsrc = Wc + (size_t)G4 * KTOT;                      // 128*16*128*768 bf16

    prep_weights<<<(G4 * KTOT + 255) / 256, 256, 0, stream>>>(W_iof, U_iof, Wc);
    prep_bx<<<(HH * BB * WW + 255) / 256, 256, 0, stream>>>(x, Bsrc);
    prep_bh_oob<<<(HH * BB * 384 + 255) / 256, 256, 0, stream>>>(Bsrc);
    prep_bh0<<<(BB * WW * 576 + 255) / 256, 256, 0, stream>>>(init_h, Bsrc);

    const unsigned short* Wcp = Wc;
    unsigned short* Bsp = Bsrc;
    const float* bp = b_iof;
    const float* icp = init_c;
    float* op = out;
    void* args[] = {&Wcp, &Bsp, &bp, &icp, &op};
    // Cooperative launch: co-residency guarantee for the spin barriers.
    hipLaunchCooperativeKernel((const void*)lstm_persist, dim3(GRIDSZ), dim3(256),
                               args, SMEM_BYTES, stream);
}

// Round 4
// 1764.829 us; speedup vs baseline: 2.8182x; 1.4116x over previous
//
#include <hip/hip_runtime.h>
#include <math.h>

#define BB 16
#define CC 192
#define NF 192
#define HH 128
#define WW 128
#define G4 768
#define KTOT 768
#define LDA 776                 // A LDS row stride in shorts (768 + 8 pad)
#define NJB 12                  // j-blocks (NF/16)
#define GRIDSZ (NJB * BB)       // 192 blocks
#define SMEM_BYTES ((64 * LDA + 128 * 24) * 2)

typedef __bf16 bf16x8 __attribute__((ext_vector_type(8)));
typedef float  f32x4  __attribute__((ext_vector_type(4)));

// Per-batch MONOTONIC arrival counter (12 arrivals/step, never reset mid-kernel).
// Relaxed agent atomics only. Slots 256B apart. Zeroed each launch by prep_weights.
__device__ unsigned g_cnt[BB * 64];

__device__ __forceinline__ float hsig(float v) {
    float y = fmaf(0.2f, v, 0.5f);
    return fminf(fmaxf(y, 0.f), 1.f);
}

// tanh(x) = 1 - 2/(e^{2x}+1); e^{2x} = 2^(2*log2e*x). Clamp to +-8 keeps the
// exp argument in range. Uses compiler builtins (hazards handled, unlike raw
// asm). ~1e-6 abs error, far below the bf16 noise floor (absmax 0.0059).
__device__ __forceinline__ float tanh_fast(float x) {
    float y = fminf(fmaxf(x, -8.f), 8.f) * 2.885390082f;   // 2*log2(e)
    float e = __builtin_amdgcn_exp2f(y);
    float r = __builtin_amdgcn_rcpf(e + 1.f);
    return fmaf(-2.f, r, 1.f);
}

__device__ __forceinline__ unsigned short f2bf(float f) {
    unsigned int u = __float_as_uint(f);
    u += 0x7fffu + ((u >> 16) & 1u);   // RNE
    return (unsigned short)(u >> 16);
}

// Wc[row=g*NF+j][k]: k<192 masked input weights; k=192+d*192+c = U tap d.
__global__ void prep_weights(const float* __restrict__ Wf,
                             const float* __restrict__ Uf,
                             unsigned short* __restrict__ Wc) {
    int idx = blockIdx.x * blockDim.x + threadIdx.x;
    if (idx < BB)                        // reset per-batch counters each launch
        g_cnt[idx * 64] = 0u;
    if (idx >= G4 * KTOT) return;
    int row = idx / KTOT;
    int k   = idx - row * KTOT;
    float v;
    if (k < CC) {
        int lim = row < 64 ? 64 : (row < 128 ? 128 : 192);
        v = (k < lim) ? Wf[row * CC + k] : 0.f;
    } else {
        int kp = k - CC;
        int d  = kp / CC;
        int c  = kp - d * CC;
        v = Uf[((size_t)row * CC + c) * 3 + d];
    }
    Wc[idx] = f2bf(v);
}

// x-part of Bsrc: Bsrc[t][b][w][c] = bf16(x[b][c][t][w]), c in [0,192).
__global__ void prep_bx(const float* __restrict__ x, unsigned short* __restrict__ Bsrc) {
    int idx = blockIdx.x * blockDim.x + threadIdx.x;   // over 128*16*128
    if (idx >= HH * BB * WW) return;
    int w = idx & (WW - 1);
    int r = idx >> 7;
    int b = r & (BB - 1);
    int t = r >> 4;
    const float* xp = x + ((size_t)b * CC * HH + t) * WW + w;
    unsigned short* dp = Bsrc + (size_t)idx * KTOT;
#pragma unroll
    for (int cc = 0; cc < CC / 8; ++cc) {
        unsigned short v[8];
#pragma unroll
        for (int i = 0; i < 8; ++i)
            v[i] = f2bf(xp[(size_t)(cc * 8 + i) * (HH * WW)]);
        *(uint4*)(dp + cc * 8) = *(uint4*)v;
    }
}

// Zero the never-written halo slots for all t: [t][b][0][192..384) and [t][b][127][576..768).
// These 64B lines are disjoint from the step-written h lines, so cached reads are safe.
__global__ void prep_bh_oob(unsigned short* __restrict__ Bsrc) {
    int idx = blockIdx.x * blockDim.x + threadIdx.x;   // 128*16*384
    if (idx >= HH * BB * 384) return;
    int u = idx % 384;
    int r = idx / 384;
    int b = r & (BB - 1);
    int t = r >> 4;
    size_t base = ((size_t)(t * BB + b) * WW) * KTOT;
    size_t off = (u < 192) ? (size_t)0 * KTOT + 192 + u
                           : (size_t)127 * KTOT + 384 + u;   // 576 + (u-192)
    Bsrc[base + off] = 0;
}

// t=0 h-part from init_h: Bsrc[0][b][w][192+d*192+c] = init_h[c][w+d-1] (0 if OOB).
__global__ void prep_bh0(const float* __restrict__ init_h, unsigned short* __restrict__ Bsrc) {
    int idx = blockIdx.x * blockDim.x + threadIdx.x;   // 16*128*576
    if (idx >= BB * WW * 576) return;
    int kp = idx % 576;
    int r  = idx / 576;
    int w  = r & (WW - 1);
    int b  = r >> 7;
    int d  = kp / CC;
    int c  = kp - d * CC;
    int wt = w + d - 1;
    float v = (wt >= 0 && wt < WW) ? init_h[c * WW + wt] : 0.f;
    Bsrc[((size_t)b * WW + w) * KTOT + CC + kp] = f2bf(v);
}

// Persistent LSTM: all 128 steps. 192 blocks x 512 threads (8 waves = 2/SIMD).
// Block = (j-tile of 16, batch b). Wave nw owns w-strip [nw*16, nw*16+16):
// M=64 (4 gates x 16 j) x N=16 per wave, acc = 4 x f32x4.
// 2 waves/SIMD overlap the exposed LLC latencies (h loads, poll, RMW) that
// dominated the 1-wave/SIMD version.
// Sync protocol identical to the round-2 kernel that passed:
//  - h-scatter = relaxed agent atomic 8B stores; __syncthreads drains them.
//  - arrive = relaxed agent fetch_add on a monotonic per-batch counter.
//  - wait = relaxed agent polls (cnt >= 12*t), workgroup-acquire compiler fence.
//  - x-part GEMM (prep data only) runs BEFORE the wait.
__global__ __launch_bounds__(512, 1) void lstm_persist(
    const unsigned short* __restrict__ Wc,
    unsigned short* __restrict__ Bsrc,
    const float* __restrict__ bias,
    const float* __restrict__ init_c,
    float* __restrict__ out)
{
    extern __shared__ unsigned short smem[];
    unsigned short (*Alds)[LDA] = (unsigned short(*)[LDA])smem;
    unsigned short (*hT)[24]    = (unsigned short(*)[24])(smem + 64 * LDA);

    const int tid  = threadIdx.x;
    const int nw   = tid >> 6;          // wave = w-strip index, 0..7
    const int lane = tid & 63;
    const int m    = lane & 15;
    const int q    = lane >> 4;
    const int jb   = blockIdx.x % NJB;
    const int b    = blockIdx.x / NJB;
    const int j0   = jb * 16;
    const int w    = nw * 16 + m;       // this lane's w column
    unsigned* const cntp = &g_cnt[b * 64];

    // ---- load A once: row r -> Wc row (r>>4)*NF + j0 + (r&15) ----
    for (int u = tid; u < 64 * 96; u += 512) {
        int r  = u / 96;
        int ko = (u - r * 96) * 8;
        int grow = (r >> 4) * NF + j0 + (r & 15);
        *(uint4*)&Alds[r][ko] = *(const uint4*)(Wc + (size_t)grow * KTOT + ko);
    }
    // ---- bias & c-state in registers ----
    float breg[4][4];
#pragma unroll
    for (int g = 0; g < 4; ++g)
#pragma unroll
        for (int r = 0; r < 4; ++r)
            breg[g][r] = bias[g * NF + j0 + q * 4 + r];
    float creg[4];
#pragma unroll
    for (int r = 0; r < 4; ++r)
        creg[r] = init_c[(j0 + q * 4 + r) * WW + w];
    __syncthreads();

    for (int t = 0; t < HH; ++t) {
        f32x4 acc[4];
#pragma unroll
        for (int g = 0; g < 4; ++g)
            acc[g] = (f32x4){breg[g][0], breg[g][1], breg[g][2], breg[g][3]};

        const unsigned short* Bn =
            Bsrc + ((size_t)(t * BB + b) * WW + w) * KTOT;

        // ---- x-part (k < 192): prefetch all 6 frags, then MFMA ----
        bf16x8 bx[6];
#pragma unroll
        for (int kc = 0; kc < 6; ++kc)
            bx[kc] = *(const bf16x8*)(Bn + kc * 32 + q * 8);
#pragma unroll
        for (int kc = 0; kc < 6; ++kc) {
            const int k = kc * 32 + q * 8;
            bf16x8 a0 = *(const bf16x8*)&Alds[ 0 + m][k];
            bf16x8 a1 = *(const bf16x8*)&Alds[16 + m][k];
            bf16x8 a2 = *(const bf16x8*)&Alds[32 + m][k];
            bf16x8 a3 = *(const bf16x8*)&Alds[48 + m][k];
            acc[0] = __builtin_amdgcn_mfma_f32_16x16x32_bf16(a0, bx[kc], acc[0], 0, 0, 0);
            acc[1] = __builtin_amdgcn_mfma_f32_16x16x32_bf16(a1, bx[kc], acc[1], 0, 0, 0);
            acc[2] = __builtin_amdgcn_mfma_f32_16x16x32_bf16(a2, bx[kc], acc[2], 0, 0, 0);
            acc[3] = __builtin_amdgcn_mfma_f32_16x16x32_bf16(a3, bx[kc], acc[3], 0, 0, 0);
        }

        // ---- wait for all 12 j-blocks' h-scatter of this step ----
        if (t > 0) {
            const unsigned need = (unsigned)(NJB * t);
            while (__hip_atomic_load(cntp, __ATOMIC_RELAXED,
                                     __HIP_MEMORY_SCOPE_AGENT) < need)
                __builtin_amdgcn_s_sleep(1);
            // compiler-only ordering: keep h loads below the spin (no L2 inv).
            __builtin_amdgcn_fence(__ATOMIC_ACQUIRE, "workgroup");
        }

        // ---- h-part (k >= 192): prefetch all 18 frags, then MFMA ----
        bf16x8 bh[18];
#pragma unroll
        for (int kc = 0; kc < 18; ++kc)
            bh[kc] = *(const bf16x8*)(Bn + 192 + kc * 32 + q * 8);
#pragma unroll
        for (int kc = 0; kc < 18; ++kc) {
            const int k = 192 + kc * 32 + q * 8;
            bf16x8 a0 = *(const bf16x8*)&Alds[ 0 + m][k];
            bf16x8 a1 = *(const bf16x8*)&Alds[16 + m][k];
            bf16x8 a2 = *(const bf16x8*)&Alds[32 + m][k];
            bf16x8 a3 = *(const bf16x8*)&Alds[48 + m][k];
            acc[0] = __builtin_amdgcn_mfma_f32_16x16x32_bf16(a0, bh[kc], acc[0], 0, 0, 0);
            acc[1] = __builtin_amdgcn_mfma_f32_16x16x32_bf16(a1, bh[kc], acc[1], 0, 0, 0);
            acc[2] = __builtin_amdgcn_mfma_f32_16x16x32_bf16(a2, bh[kc], acc[2], 0, 0, 0);
            acc[3] = __builtin_amdgcn_mfma_f32_16x16x32_bf16(a3, bh[kc], acc[3], 0, 0, 0);
        }

        // ---- epilogue: gates + c/h update, h -> LDS transpose ----
#pragma unroll
        for (int r = 0; r < 4; ++r) {
            const int j = j0 + q * 4 + r;
            float og = hsig(acc[0][r]);
            float fg = hsig(acc[1][r]);
            float ig = hsig(acc[2][r]);
            float gg = tanh_fast(acc[3][r]);
            float cn = fmaf(fg, creg[r], ig * gg);
            creg[r] = cn;
            float hn = og * tanh_fast(cn);
            out[(((size_t)b * NF + j) * HH + t) * WW + w] = hn;
            hT[w][q * 4 + r] = f2bf(hn);
        }
        __syncthreads();

        // ---- scatter h into next step's B source (8B agent stores), arrive ----
        if (t < HH - 1) {
            unsigned short* Bns = Bsrc + ((size_t)((t + 1) * BB + b) * WW) * KTOT;
            if (tid < 384) {
                int d  = tid >> 7;
                int w2 = tid & 127;
                int ws = w2 + d - 1;
                if (ws >= 0 && ws < WW) {
                    const unsigned long long* s8 =
                        (const unsigned long long*)&hT[ws][0];
                    unsigned long long* d8 = (unsigned long long*)
                        (Bns + (size_t)w2 * KTOT + CC + d * CC + j0);
#pragma unroll
                    for (int e = 0; e < 4; ++e)
                        __hip_atomic_store(d8 + e, s8[e], __ATOMIC_RELAXED,
                                           __HIP_MEMORY_SCOPE_AGENT);
                }
            }
            // vmcnt(0) inside __syncthreads drains the sc1 stores to the
            // coherence point for ALL waves before tid 0 publishes arrival.
            __syncthreads();
            if (tid == 0)
                __hip_atomic_fetch_add(cntp, 1u, __ATOMIC_RELAXED,
                                       __HIP_MEMORY_SCOPE_AGENT);
        }
    }
}

extern "C" void kernel_launch(void* const* d_in, const int* in_sizes, int n_in,
                              void* d_out, int out_size, void* d_ws, size_t ws_size,
                              hipStream_t stream) {
    const float* x      = (const float*)d_in[0];
    const float* W_iof  = (const float*)d_in[1];
    const float* U_iof  = (const float*)d_in[2];
    const float* b_iof  = (const float*)d_in[3];
    const float* init_h = (const float*)d_in[4];
    const float* init_c = (const float*)d_in[5];
    float* out = (float*)d_out;

    unsigned short* Wc   = (unsigned short*)d_ws;                       // 768*768 bf16
    unsigned short* Bsrc = Wc + (size_t)G4 * KTOT;                      // 128*16*128*768 bf16

    prep_weights<<<(G4 * KTOT + 255) / 256, 256, 0, stream>>>(W_iof, U_iof, Wc);
    prep_bx<<<(HH * BB * WW + 255) / 256, 256, 0, stream>>>(x, Bsrc);
    prep_bh_oob<<<(HH * BB * 384 + 255) / 256, 256, 0, stream>>>(Bsrc);
    prep_bh0<<<(BB * WW * 576 + 255) / 256, 256, 0, stream>>>(init_h, Bsrc);

    const unsigned short* Wcp = Wc;
    unsigned short* Bsp = Bsrc;
    const float* bp = b_iof;
    const float* icp = init_c;
    float* op = out;
    void* args[] = {&Wcp, &Bsp, &bp, &icp, &op};
    // Cooperative launch: co-residency guarantee for the spin barriers.
    hipLaunchCooperativeKernel((const void*)lstm_persist, dim3(GRIDSZ), dim3(512),
                               args, SMEM_BYTES, stream);
}

// Round 5
// 1459.437 us; speedup vs baseline: 3.4080x; 1.2093x over previous
//
#include <hip/hip_runtime.h>
#include <math.h>

#define BB 16
#define CC 192
#define NF 192
#define HH 128
#define WW 128
#define G4 768
#define KTOT 768
#define LDA 776                 // A LDS row stride in shorts (768 + 8 pad)
#define NJB 12                  // j-blocks (NF/16)
#define GRIDSZ (NJB * BB)       // 192 blocks
#define SMEM_BYTES (64 * LDA * 2)   // A tile only (hT eliminated)

typedef __bf16 bf16x8 __attribute__((ext_vector_type(8)));
typedef float  f32x4  __attribute__((ext_vector_type(4)));

// Per-batch MONOTONIC arrival counter (12 arrivals/step, never reset mid-kernel).
// Relaxed agent atomics only. Slots 256B apart. Zeroed each launch by prep_weights.
__device__ unsigned g_cnt[BB * 64];

__device__ __forceinline__ float hsig(float v) {
    float y = fmaf(0.2f, v, 0.5f);
    return fminf(fmaxf(y, 0.f), 1.f);
}

// tanh(x) = 1 - 2/(e^{2x}+1); e^{2x} = 2^(2*log2e*x). Clamp to +-8 keeps the
// exp argument in range. Compiler builtins (hazards handled). ~1e-6 abs error,
// far below the bf16 noise floor (absmax 0.0059).
__device__ __forceinline__ float tanh_fast(float x) {
    float y = fminf(fmaxf(x, -8.f), 8.f) * 2.885390082f;   // 2*log2(e)
    float e = __builtin_amdgcn_exp2f(y);
    float r = __builtin_amdgcn_rcpf(e + 1.f);
    return fmaf(-2.f, r, 1.f);
}

__device__ __forceinline__ unsigned short f2bf(float f) {
    unsigned int u = __float_as_uint(f);
    u += 0x7fffu + ((u >> 16) & 1u);   // RNE
    return (unsigned short)(u >> 16);
}

// Wc[row=g*NF+j][k]: k<192 masked input weights; k=192+d*192+c = U tap d.
__global__ void prep_weights(const float* __restrict__ Wf,
                             const float* __restrict__ Uf,
                             unsigned short* __restrict__ Wc) {
    int idx = blockIdx.x * blockDim.x + threadIdx.x;
    if (idx < BB)                        // reset per-batch counters each launch
        g_cnt[idx * 64] = 0u;
    if (idx >= G4 * KTOT) return;
    int row = idx / KTOT;
    int k   = idx - row * KTOT;
    float v;
    if (k < CC) {
        int lim = row < 64 ? 64 : (row < 128 ? 128 : 192);
        v = (k < lim) ? Wf[row * CC + k] : 0.f;
    } else {
        int kp = k - CC;
        int d  = kp / CC;
        int c  = kp - d * CC;
        v = Uf[((size_t)row * CC + c) * 3 + d];
    }
    Wc[idx] = f2bf(v);
}

// x-part of Bsrc: Bsrc[t][b][w][c] = bf16(x[b][c][t][w]), c in [0,192).
__global__ void prep_bx(const float* __restrict__ x, unsigned short* __restrict__ Bsrc) {
    int idx = blockIdx.x * blockDim.x + threadIdx.x;   // over 128*16*128
    if (idx >= HH * BB * WW) return;
    int w = idx & (WW - 1);
    int r = idx >> 7;
    int b = r & (BB - 1);
    int t = r >> 4;
    const float* xp = x + ((size_t)b * CC * HH + t) * WW + w;
    unsigned short* dp = Bsrc + (size_t)idx * KTOT;
#pragma unroll
    for (int cc = 0; cc < CC / 8; ++cc) {
        unsigned short v[8];
#pragma unroll
        for (int i = 0; i < 8; ++i)
            v[i] = f2bf(xp[(size_t)(cc * 8 + i) * (HH * WW)]);
        *(uint4*)(dp + cc * 8) = *(uint4*)v;
    }
}

// Zero the never-written halo slots for all t: [t][b][0][192..384) and [t][b][127][576..768).
// These 64B lines are disjoint from the step-written h lines, so cached reads are safe.
__global__ void prep_bh_oob(unsigned short* __restrict__ Bsrc) {
    int idx = blockIdx.x * blockDim.x + threadIdx.x;   // 128*16*384
    if (idx >= HH * BB * 384) return;
    int u = idx % 384;
    int r = idx / 384;
    int b = r & (BB - 1);
    int t = r >> 4;
    size_t base = ((size_t)(t * BB + b) * WW) * KTOT;
    size_t off = (u < 192) ? (size_t)0 * KTOT + 192 + u
                           : (size_t)127 * KTOT + 384 + u;   // 576 + (u-192)
    Bsrc[base + off] = 0;
}

// t=0 h-part from init_h: Bsrc[0][b][w][192+d*192+c] = init_h[c][w+d-1] (0 if OOB).
__global__ void prep_bh0(const float* __restrict__ init_h, unsigned short* __restrict__ Bsrc) {
    int idx = blockIdx.x * blockDim.x + threadIdx.x;   // 16*128*576
    if (idx >= BB * WW * 576) return;
    int kp = idx % 576;
    int r  = idx / 576;
    int w  = r & (WW - 1);
    int b  = r >> 7;
    int d  = kp / CC;
    int c  = kp - d * CC;
    int wt = w + d - 1;
    float v = (wt >= 0 && wt < WW) ? init_h[c * WW + wt] : 0.f;
    Bsrc[((size_t)b * WW + w) * KTOT + CC + kp] = f2bf(v);
}

// Persistent LSTM: all 128 steps. 192 blocks x 512 threads (8 waves = 2/SIMD).
// Block = (j-tile of 16, batch b). Wave nw owns w-strip [nw*16, nw*16+16):
// M=64 (4 gates x 16 j) x N=16 per wave, acc = 4 x f32x4.
// This round: x-frags prefetched one step ahead (HBM-cold loads hidden under
// the previous step's h phase); h scattered straight from registers (hT LDS
// round-trip and one __syncthreads removed); out[] stores moved after arrival.
// Sync protocol byte-identical to the round-4 kernel that passed.
__global__ __launch_bounds__(512, 1) void lstm_persist(
    const unsigned short* __restrict__ Wc,
    unsigned short* __restrict__ Bsrc,
    const float* __restrict__ bias,
    const float* __restrict__ init_c,
    float* __restrict__ out)
{
    extern __shared__ unsigned short smem[];
    unsigned short (*Alds)[LDA] = (unsigned short(*)[LDA])smem;

    const int tid  = threadIdx.x;
    const int nw   = tid >> 6;          // wave = w-strip index, 0..7
    const int lane = tid & 63;
    const int m    = lane & 15;
    const int q    = lane >> 4;
    const int jb   = blockIdx.x % NJB;
    const int b    = blockIdx.x / NJB;
    const int j0   = jb * 16;
    const int w    = nw * 16 + m;       // this lane's w column
    unsigned* const cntp = &g_cnt[b * 64];

    // ---- load A once: row r -> Wc row (r>>4)*NF + j0 + (r&15) ----
    for (int u = tid; u < 64 * 96; u += 512) {
        int r  = u / 96;
        int ko = (u - r * 96) * 8;
        int grow = (r >> 4) * NF + j0 + (r & 15);
        *(uint4*)&Alds[r][ko] = *(const uint4*)(Wc + (size_t)grow * KTOT + ko);
    }
    // ---- bias & c-state in registers ----
    float breg[4][4];
#pragma unroll
    for (int g = 0; g < 4; ++g)
#pragma unroll
        for (int r = 0; r < 4; ++r)
            breg[g][r] = bias[g * NF + j0 + q * 4 + r];
    float creg[4];
#pragma unroll
    for (int r = 0; r < 4; ++r)
        creg[r] = init_c[(j0 + q * 4 + r) * WW + w];
    __syncthreads();

    // ---- prefetch x-frags for t=0 ----
    bf16x8 bxc[6], bxn[6];
    {
        const unsigned short* B0 = Bsrc + ((size_t)b * WW + w) * KTOT;
#pragma unroll
        for (int kc = 0; kc < 6; ++kc)
            bxc[kc] = *(const bf16x8*)(B0 + kc * 32 + q * 8);
    }

    for (int t = 0; t < HH; ++t) {
        f32x4 acc[4];
#pragma unroll
        for (int g = 0; g < 4; ++g)
            acc[g] = (f32x4){breg[g][0], breg[g][1], breg[g][2], breg[g][3]};

        const unsigned short* Bn =
            Bsrc + ((size_t)(t * BB + b) * WW + w) * KTOT;

        // ---- x-part (k < 192): frags already in registers (prefetched) ----
#pragma unroll
        for (int kc = 0; kc < 6; ++kc) {
            const int k = kc * 32 + q * 8;
            bf16x8 a0 = *(const bf16x8*)&Alds[ 0 + m][k];
            bf16x8 a1 = *(const bf16x8*)&Alds[16 + m][k];
            bf16x8 a2 = *(const bf16x8*)&Alds[32 + m][k];
            bf16x8 a3 = *(const bf16x8*)&Alds[48 + m][k];
            acc[0] = __builtin_amdgcn_mfma_f32_16x16x32_bf16(a0, bxc[kc], acc[0], 0, 0, 0);
            acc[1] = __builtin_amdgcn_mfma_f32_16x16x32_bf16(a1, bxc[kc], acc[1], 0, 0, 0);
            acc[2] = __builtin_amdgcn_mfma_f32_16x16x32_bf16(a2, bxc[kc], acc[2], 0, 0, 0);
            acc[3] = __builtin_amdgcn_mfma_f32_16x16x32_bf16(a3, bxc[kc], acc[3], 0, 0, 0);
        }

        // ---- wait for all 12 j-blocks' h-scatter of this step ----
        if (t > 0) {
            const unsigned need = (unsigned)(NJB * t);
            while (__hip_atomic_load(cntp, __ATOMIC_RELAXED,
                                     __HIP_MEMORY_SCOPE_AGENT) < need)
                __builtin_amdgcn_s_sleep(1);
            // compiler-only ordering: keep h loads below the spin (no L2 inv).
            __builtin_amdgcn_fence(__ATOMIC_ACQUIRE, "workgroup");
        }

        // ---- h-part (k >= 192): issue all 18 frag loads ----
        bf16x8 bh[18];
#pragma unroll
        for (int kc = 0; kc < 18; ++kc)
            bh[kc] = *(const bf16x8*)(Bn + 192 + kc * 32 + q * 8);

        // ---- prefetch next step's x-frags (HBM-cold; issued after bh so the
        //      bh wait leaves them in flight, hidden under h-MFMA+epilogue) ----
        if (t < HH - 1) {
            const unsigned short* Bx = Bn + (size_t)BB * WW * KTOT;
#pragma unroll
            for (int kc = 0; kc < 6; ++kc)
                bxn[kc] = *(const bf16x8*)(Bx + kc * 32 + q * 8);
        }

#pragma unroll
        for (int kc = 0; kc < 18; ++kc) {
            const int k = 192 + kc * 32 + q * 8;
            bf16x8 a0 = *(const bf16x8*)&Alds[ 0 + m][k];
            bf16x8 a1 = *(const bf16x8*)&Alds[16 + m][k];
            bf16x8 a2 = *(const bf16x8*)&Alds[32 + m][k];
            bf16x8 a3 = *(const bf16x8*)&Alds[48 + m][k];
            acc[0] = __builtin_amdgcn_mfma_f32_16x16x32_bf16(a0, bh[kc], acc[0], 0, 0, 0);
            acc[1] = __builtin_amdgcn_mfma_f32_16x16x32_bf16(a1, bh[kc], acc[1], 0, 0, 0);
            acc[2] = __builtin_amdgcn_mfma_f32_16x16x32_bf16(a2, bh[kc], acc[2], 0, 0, 0);
            acc[3] = __builtin_amdgcn_mfma_f32_16x16x32_bf16(a3, bh[kc], acc[3], 0, 0, 0);
        }

        // ---- epilogue: gates + c/h update (all in registers) ----
        float hn[4];
#pragma unroll
        for (int r = 0; r < 4; ++r) {
            float og = hsig(acc[0][r]);
            float fg = hsig(acc[1][r]);
            float ig = hsig(acc[2][r]);
            float gg = tanh_fast(acc[3][r]);
            float cn = fmaf(fg, creg[r], ig * gg);
            creg[r] = cn;
            hn[r] = og * tanh_fast(cn);
        }

        // ---- scatter h straight from registers, then arrive ----
        if (t < HH - 1) {
            unsigned long long pk =
                  (unsigned long long)f2bf(hn[0])
                | ((unsigned long long)f2bf(hn[1]) << 16)
                | ((unsigned long long)f2bf(hn[2]) << 32)
                | ((unsigned long long)f2bf(hn[3]) << 48);
            unsigned short* Bns =
                Bsrc + ((size_t)((t + 1) * BB + b) * WW) * KTOT;
            const int jo = CC + j0 + q * 4;
            // tap d: destination row w2 = w + 1 - d  (this lane's h feeds
            // gates at rows w-1, w, w+1 of the next step)
            __hip_atomic_store((unsigned long long*)
                (Bns + (size_t)w * KTOT + jo + CC), pk,
                __ATOMIC_RELAXED, __HIP_MEMORY_SCOPE_AGENT);          // d=1
            if (w < WW - 1)
                __hip_atomic_store((unsigned long long*)
                    (Bns + (size_t)(w + 1) * KTOT + jo), pk,
                    __ATOMIC_RELAXED, __HIP_MEMORY_SCOPE_AGENT);      // d=0
            if (w > 0)
                __hip_atomic_store((unsigned long long*)
                    (Bns + (size_t)(w - 1) * KTOT + jo + 2 * CC), pk,
                    __ATOMIC_RELAXED, __HIP_MEMORY_SCOPE_AGENT);      // d=2
            // each wave drains its agent stores to the coherence point, then
            // the block barrier orders all waves before tid 0 publishes.
            asm volatile("s_waitcnt vmcnt(0)" ::: "memory");
            __syncthreads();
            if (tid == 0)
                __hip_atomic_fetch_add(cntp, 1u, __ATOMIC_RELAXED,
                                       __HIP_MEMORY_SCOPE_AGENT);
        }

        // ---- out[] stores off the arrival critical path ----
#pragma unroll
        for (int r = 0; r < 4; ++r)
            out[(((size_t)b * NF + j0 + q * 4 + r) * HH + t) * WW + w] = hn[r];

        // rotate x prefetch buffers
#pragma unroll
        for (int kc = 0; kc < 6; ++kc)
            bxc[kc] = bxn[kc];
    }
}

extern "C" void kernel_launch(void* const* d_in, const int* in_sizes, int n_in,
                              void* d_out, int out_size, void* d_ws, size_t ws_size,
                              hipStream_t stream) {
    const float* x      = (const float*)d_in[0];
    const float* W_iof  = (const float*)d_in[1];
    const float* U_iof  = (const float*)d_in[2];
    const float* b_iof  = (const float*)d_in[3];
    const float* init_h = (const float*)d_in[4];
    const float* init_c = (const float*)d_in[5];
    float* out = (float*)d_out;

    unsigned short* Wc   = (unsigned short*)d_ws;                       // 768*768 bf16
    unsigned short* Bsrc = Wc + (size_t)G4 * KTOT;                      // 128*16*128*768 bf16

    prep_weights<<<(G4 * KTOT + 255) / 256, 256, 0, stream>>>(W_iof, U_iof, Wc);
    prep_bx<<<(HH * BB * WW + 255) / 256, 256, 0, stream>>>(x, Bsrc);
    prep_bh_oob<<<(HH * BB * 384 + 255) / 256, 256, 0, stream>>>(Bsrc);
    prep_bh0<<<(BB * WW * 576 + 255) / 256, 256, 0, stream>>>(init_h, Bsrc);

    const unsigned short* Wcp = Wc;
    unsigned short* Bsp = Bsrc;
    const float* bp = b_iof;
    const float* icp = init_c;
    float* op = out;
    void* args[] = {&Wcp, &Bsp, &bp, &icp, &op};
    // Cooperative launch: co-residency guarantee for the spin barriers.
    hipLaunchCooperativeKernel((const void*)lstm_persist, dim3(GRIDSZ), dim3(512),
                               args, SMEM_BYTES, stream);
}